// Round 5
// baseline (775.139 us; speedup 1.0000x reference)
//
#include <hip/hip_runtime.h>
#include <cstdint>
#include <cstddef>

#define NN 100000
#define NP 100032
#define NE 800000
#define NG 256
#define NL 5
#define EPS 1e-5f

typedef __bf16 bf16x8 __attribute__((ext_vector_type(8)));
typedef float f32x4 __attribute__((ext_vector_type(4)));

__device__ __forceinline__ float bf2f(unsigned short u) {
  union { unsigned int i; float f; } x; x.i = ((unsigned int)u) << 16; return x.f;
}
__device__ __forceinline__ unsigned short f2bf(float f) {
  union { float f; unsigned int i; } x; x.f = f;
  unsigned int r = x.i + 0x7fffu + ((x.i >> 16) & 1u);
  return (unsigned short)(r >> 16);
}

// ---------------- init: A = bf16(atom_emb[x]) ----------------
__global__ __launch_bounds__(256) void init_h_k(const int* __restrict__ x,
                                                const float* __restrict__ atom_emb,
                                                unsigned short* __restrict__ A) {
  int i = blockIdx.x * 256 + threadIdx.x;   // NN*8 exactly
  int n = i >> 3, c0 = (i & 7) * 8;
  const float* p = atom_emb + (size_t)x[n] * 64 + c0;
  float4 v0 = *(const float4*)p;
  float4 v1 = *(const float4*)(p + 4);
  union { bf16x8 b; unsigned short u[8]; } o;
  o.u[0] = f2bf(v0.x); o.u[1] = f2bf(v0.y); o.u[2] = f2bf(v0.z); o.u[3] = f2bf(v0.w);
  o.u[4] = f2bf(v1.x); o.u[5] = f2bf(v1.y); o.u[6] = f2bf(v1.z); o.u[7] = f2bf(v1.w);
  *(bf16x8*)(A + (size_t)n * 64 + c0) = o.b;
}

// ---------------- weight transpose+convert: Wt[l][col][k] = bf16(W[l][k][col]) ----------------
__global__ __launch_bounds__(256) void wconv_k(const float* __restrict__ W1,
                                               const float* __restrict__ W2,
                                               unsigned short* __restrict__ Wt1,
                                               unsigned short* __restrict__ Wt2) {
  int i = blockIdx.x * 256 + threadIdx.x;
  const int S = NL * 128 * 64;   // 40960
  if (i < S) {
    int l = i / (128 * 64), r = i % (128 * 64);
    int c = r / 64, k = r % 64;
    Wt1[i] = f2bf(W1[(size_t)l * 64 * 128 + (size_t)k * 128 + c]);
  } else if (i < 2 * S) {
    int j = i - S;
    int l = j / (128 * 64), r = j % (128 * 64);
    int c = r / 128, k = r % 128;
    Wt2[j] = f2bf(W2[(size_t)l * 128 * 64 + (size_t)k * 64 + c]);
  }
}

// ---------------- CSR build ----------------
__global__ __launch_bounds__(256) void hist_k(const int* __restrict__ ei,
                                              int* __restrict__ cnt) {
  int e = blockIdx.x * 256 + threadIdx.x;
  if (e >= NE) return;
  atomicAdd(&cnt[ei[NE + e]], 1);
}

__global__ __launch_bounds__(256) void scan1_k(const int* __restrict__ cnt,
                                               int* __restrict__ rs,
                                               int* __restrict__ bsum) {
  __shared__ int sh[256];
  int t = threadIdx.x;
  int base = blockIdx.x * 1024 + t * 4;
  int v0 = 0, v1 = 0, v2 = 0, v3 = 0;
  if (base + 0 < NN) v0 = cnt[base + 0];
  if (base + 1 < NN) v1 = cnt[base + 1];
  if (base + 2 < NN) v2 = cnt[base + 2];
  if (base + 3 < NN) v3 = cnt[base + 3];
  int tsum = v0 + v1 + v2 + v3;
  sh[t] = tsum;
  __syncthreads();
  for (int off = 1; off < 256; off <<= 1) {
    int x = (t >= off) ? sh[t - off] : 0;
    __syncthreads();
    sh[t] += x;
    __syncthreads();
  }
  int excl = sh[t] - tsum;
  if (base + 0 < NN) rs[base + 0] = excl;
  if (base + 1 < NN) rs[base + 1] = excl + v0;
  if (base + 2 < NN) rs[base + 2] = excl + v0 + v1;
  if (base + 3 < NN) rs[base + 3] = excl + v0 + v1 + v2;
  if (t == 255) bsum[blockIdx.x] = sh[255];
}

__global__ void scan2_k(const int* __restrict__ bsum, int* __restrict__ bofs, int nb) {
  if (threadIdx.x == 0 && blockIdx.x == 0) {
    int run = 0;
    for (int i = 0; i < nb; ++i) { bofs[i] = run; run += bsum[i]; }
  }
}

__global__ __launch_bounds__(256) void scan3_k(int* __restrict__ rs,
                                               const int* __restrict__ bofs,
                                               int* __restrict__ cursor) {
  int i = blockIdx.x * 256 + threadIdx.x;
  if (i < NN) {
    int v = rs[i] + bofs[i >> 10];
    rs[i] = v;
    cursor[i] = v;
  } else if (i <= NP) {
    rs[i] = NE;   // padded rows: empty
  }
}

// XCD-banded scatter (keeps per-band epack slice XCD-local so stores merge)
__global__ __launch_bounds__(256) void scatter_k(const int* __restrict__ ei,
                                                 const int* __restrict__ eattr,
                                                 int* __restrict__ cursor,
                                                 int* __restrict__ epack) {
  int band = blockIdx.x & 7;
  int e = (blockIdx.x >> 3) * 256 + threadIdx.x;
  if (e >= NE) return;
  int d = ei[NE + e];
  if (d / 12500 != band) return;
  int slot = atomicAdd(&cursor[d], 1);
  epack[slot] = (ei[e] << 3) | eattr[e];
}

// ---------------- fused: gather (+prev-BN) -> LDS tile -> MFMA gemm1 -> z1 + stats ----
// hsrc(n) = MODE ? relu(A[n]*scl+shf) : A[n]; B-row = hsrc(w) + sum relu(hsrc(src)+bond)
// block = 64 rows, 4 waves (wave w: rows w*16..w*16+15). lane=(es 0-3, cg 0-15).
template <int MODE>
__global__ __launch_bounds__(256) void aggr_gemm1_k(const int* __restrict__ rowstart,
                                                    const int* __restrict__ epack,
                                                    const float* __restrict__ bond,
                                                    const unsigned short* __restrict__ A,
                                                    const float* __restrict__ stat2prev,
                                                    const float* __restrict__ g,
                                                    const float* __restrict__ be,
                                                    const unsigned short* __restrict__ Wt,
                                                    const float* __restrict__ bias,
                                                    unsigned short* __restrict__ z1b,
                                                    float* __restrict__ stat1f) {
  __shared__ float bl[320];                 // bond [5][64]
  __shared__ float scl64[64], shf64[64];
  __shared__ unsigned short Bs[64][72];     // gathered tile, pad 72
  __shared__ unsigned short Zs[64][136];    // z1 output tile, pad 136
  __shared__ float sred[256];
  int tid = threadIdx.x;
  for (int j = tid; j < 320; j += 256) bl[j] = bond[j];
  if (MODE && tid < 64) {
    float s = 0.f, s2 = 0.f;
#pragma unroll
    for (int r = 0; r < 8; ++r) { s += stat2prev[r * 128 + tid]; s2 += stat2prev[r * 128 + 64 + tid]; }
    float mean = s * (1.f / NN);
    float var = fmaxf(s2 * (1.f / NN) - mean * mean, 0.f);
    float sc = g[tid] * rsqrtf(var + EPS);
    scl64[tid] = sc;
    shf64[tid] = be[tid] - mean * sc;
  }
  sred[tid] = 0.f;
  __syncthreads();

  int w = tid >> 6, lane = tid & 63;
  int es = lane >> 4, cg = lane & 15, c0 = cg * 4;
  float s0 = 1.f, s1 = 1.f, s2c = 1.f, s3 = 1.f, f0 = 0.f, f1 = 0.f, f2 = 0.f, f3 = 0.f;
  if (MODE) {
    s0 = scl64[c0]; s1 = scl64[c0 + 1]; s2c = scl64[c0 + 2]; s3 = scl64[c0 + 3];
    f0 = shf64[c0]; f1 = shf64[c0 + 1]; f2 = shf64[c0 + 2]; f3 = shf64[c0 + 3];
  }
  int w16 = blockIdx.x * 64 + w * 16;
  int rsv = rowstart[w16 + (lane <= 16 ? lane : 16)];
  for (int r = 0; r < 16; ++r) {
    int s = __shfl(rsv, r), e = __shfl(rsv, r + 1);
    float a0 = 0.f, a1 = 0.f, a2 = 0.f, a3 = 0.f;
    for (int base = s; base < e; base += 64) {
      int m = e - base; if (m > 64) m = 64;
      int pk = (lane < m) ? epack[base + lane] : 0;
      int iters = (m + 3) >> 2;
      for (int i = 0; i < iters; ++i) {
        int idx = i * 4 + es;
        int p = __shfl(pk, idx);
        if (idx < m) {
          ushort4 hv = *(const ushort4*)(A + (size_t)(p >> 3) * 64 + c0);
          float4 bv = *(const float4*)&bl[(p & 7) * 64 + c0];
          float v0 = bf2f(hv.x), v1 = bf2f(hv.y), v2 = bf2f(hv.z), v3 = bf2f(hv.w);
          if (MODE) {
            v0 = fmaxf(fmaf(v0, s0, f0), 0.f);
            v1 = fmaxf(fmaf(v1, s1, f1), 0.f);
            v2 = fmaxf(fmaf(v2, s2c, f2), 0.f);
            v3 = fmaxf(fmaf(v3, s3, f3), 0.f);
          }
          a0 += fmaxf(v0 + bv.x, 0.f);
          a1 += fmaxf(v1 + bv.y, 0.f);
          a2 += fmaxf(v2 + bv.z, 0.f);
          a3 += fmaxf(v3 + bv.w, 0.f);
        }
      }
    }
    a0 += __shfl_xor(a0, 16); a0 += __shfl_xor(a0, 32);
    a1 += __shfl_xor(a1, 16); a1 += __shfl_xor(a1, 32);
    a2 += __shfl_xor(a2, 16); a2 += __shfl_xor(a2, 32);
    a3 += __shfl_xor(a3, 16); a3 += __shfl_xor(a3, 32);
    if (es == 0) {
      ushort4 rv = *(const ushort4*)(A + (size_t)(w16 + r) * 64 + c0);
      float r0 = bf2f(rv.x), r1 = bf2f(rv.y), r2 = bf2f(rv.z), r3 = bf2f(rv.w);
      if (MODE) {
        r0 = fmaxf(fmaf(r0, s0, f0), 0.f);
        r1 = fmaxf(fmaf(r1, s1, f1), 0.f);
        r2 = fmaxf(fmaf(r2, s2c, f2), 0.f);
        r3 = fmaxf(fmaf(r3, s3, f3), 0.f);
      }
      ushort4 o;
      o.x = f2bf(a0 + r0); o.y = f2bf(a1 + r1);
      o.z = f2bf(a2 + r2); o.w = f2bf(a3 + r3);
      *(ushort4*)&Bs[w * 16 + r][cg * 4] = o;
    }
  }
  __syncthreads();

  // ---- phase 2: MFMA 16x16x32, wave w does rows w*16..15, all 128 cols ----
  int rlo = lane & 15, khi = lane >> 4;
  bf16x8 a0 = *(const bf16x8*)&Bs[w * 16 + rlo][khi * 8];
  bf16x8 a1 = *(const bf16x8*)&Bs[w * 16 + rlo][khi * 8 + 32];
#pragma unroll
  for (int ct = 0; ct < 8; ++ct) {
    const bf16x8* bp = (const bf16x8*)(Wt + ((size_t)(ct * 16 + rlo) * 64 + khi * 8));
    f32x4 acc;
    acc[0] = 0.f; acc[1] = 0.f; acc[2] = 0.f; acc[3] = 0.f;
    acc = __builtin_amdgcn_mfma_f32_16x16x32_bf16(a0, bp[0], acc, 0, 0, 0);
    acc = __builtin_amdgcn_mfma_f32_16x16x32_bf16(a1, bp[4], acc, 0, 0, 0);
    int c = ct * 16 + rlo;
    float bs = bias[c];
    float s = 0.f, s2 = 0.f;
#pragma unroll
    for (int q = 0; q < 4; ++q) {
      int brow = w * 16 + khi * 4 + q;
      float v = acc[q] + bs;
      unsigned short ub = f2bf(v);
      Zs[brow][c] = ub;
      float vf = bf2f(ub);
      if (blockIdx.x * 64 + brow < NN) { s += vf; s2 += vf * vf; }
    }
    atomicAdd(&sred[c], s);
    atomicAdd(&sred[128 + c], s2);
  }
  __syncthreads();

  // coalesced z1 write-out: 64 rows x 128 cols bf16, 4 vecs/thread
  int orow = tid >> 2, oc0 = (tid & 3) * 32;
  unsigned short* zp = z1b + (size_t)(blockIdx.x * 64 + orow) * 128 + oc0;
#pragma unroll
  for (int v = 0; v < 4; ++v)
    *(bf16x8*)(zp + v * 8) = *(const bf16x8*)&Zs[orow][oc0 + v * 8];
  atomicAdd(&stat1f[(blockIdx.x & 7) * 256 + tid], sred[tid]);
}

// ---------------- gemm2 MFMA: z2 = relu(bn1(z1)) @ W2 + b2, BN1 finalize in prologue ----------------
__global__ __launch_bounds__(256) void gemm2_k(const unsigned short* __restrict__ z1b,
                                               const unsigned short* __restrict__ Wt,
                                               const float* __restrict__ bias,
                                               const float* __restrict__ g,
                                               const float* __restrict__ be,
                                               const float* __restrict__ stat1f,
                                               unsigned short* __restrict__ z2b,
                                               float* __restrict__ stat2f) {
  __shared__ float scl[128], shf[128], sred[128];
  __shared__ unsigned short Zs[64][72];
  int tid = threadIdx.x;
  if (tid < 128) {
    float s = 0.f, s2 = 0.f;
#pragma unroll
    for (int r = 0; r < 8; ++r) { s += stat1f[r * 256 + tid]; s2 += stat1f[r * 256 + 128 + tid]; }
    float mean = s * (1.f / NN);
    float var = fmaxf(s2 * (1.f / NN) - mean * mean, 0.f);
    float sc = g[tid] * rsqrtf(var + EPS);
    scl[tid] = sc;
    shf[tid] = be[tid] - mean * sc;
    sred[tid] = 0.f;
  }
  __syncthreads();
  int w = tid >> 6, lane = tid & 63;
  int rlo = lane & 15, khi = lane >> 4;
  int row0 = blockIdx.x * 64 + w * 16;
  const unsigned short* zr = z1b + (size_t)(row0 + rlo) * 128;
  f32x4 acc[4];
#pragma unroll
  for (int ct = 0; ct < 4; ++ct) { acc[ct][0] = 0.f; acc[ct][1] = 0.f; acc[ct][2] = 0.f; acc[ct][3] = 0.f; }
#pragma unroll
  for (int kc = 0; kc < 4; ++kc) {
    int k0 = kc * 32 + khi * 8;
    union { bf16x8 b; unsigned short u[8]; } raw, af;
    raw.b = *(const bf16x8*)(zr + k0);
#pragma unroll
    for (int j = 0; j < 8; ++j) {
      float vf = fmaf(bf2f(raw.u[j]), scl[k0 + j], shf[k0 + j]);
      af.u[j] = f2bf(fmaxf(vf, 0.f));
    }
#pragma unroll
    for (int ct = 0; ct < 4; ++ct) {
      const bf16x8* bp = (const bf16x8*)(Wt + ((size_t)(ct * 16 + rlo) * 128 + k0));
      acc[ct] = __builtin_amdgcn_mfma_f32_16x16x32_bf16(af.b, bp[0], acc[ct], 0, 0, 0);
    }
  }
#pragma unroll
  for (int ct = 0; ct < 4; ++ct) {
    int c = ct * 16 + rlo;
    float bs = bias[c];
    float s = 0.f, s2 = 0.f;
#pragma unroll
    for (int q = 0; q < 4; ++q) {
      int brow = w * 16 + khi * 4 + q;
      float v = acc[ct][q] + bs;
      unsigned short ub = f2bf(v);
      Zs[brow][c] = ub;
      float vf = bf2f(ub);
      if (blockIdx.x * 64 + brow < NN) { s += vf; s2 += vf * vf; }
    }
    atomicAdd(&sred[c], s);
    atomicAdd(&sred[64 + c], s2);
  }
  __syncthreads();
  // coalesced z2 write-out: 64 rows x 64 cols bf16, 2 vecs/thread
#pragma unroll
  for (int pass = 0; pass < 2; ++pass) {
    int orow = pass * 32 + (tid >> 3), oc0 = (tid & 7) * 8;
    *(bf16x8*)(z2b + (size_t)(blockIdx.x * 64 + orow) * 64 + oc0) =
        *(const bf16x8*)&Zs[orow][oc0];
  }
  if (tid < 128) atomicAdd(&stat2f[(blockIdx.x & 7) * 128 + tid], sred[tid]);
}

// ---------------- final BN apply (no relu) -> f32 h output; BN2 finalize in prologue ----------------
__global__ __launch_bounds__(256) void bn_final_k(const unsigned short* __restrict__ A,
                                                  const float* __restrict__ stat2f,
                                                  const float* __restrict__ g,
                                                  const float* __restrict__ be,
                                                  float* __restrict__ hf) {
  __shared__ float scl[64], shf[64];
  int tid = threadIdx.x;
  if (tid < 64) {
    float s = 0.f, s2 = 0.f;
#pragma unroll
    for (int r = 0; r < 8; ++r) { s += stat2f[r * 128 + tid]; s2 += stat2f[r * 128 + 64 + tid]; }
    float mean = s * (1.f / NN);
    float var = fmaxf(s2 * (1.f / NN) - mean * mean, 0.f);
    float sc = g[tid] * rsqrtf(var + EPS);
    scl[tid] = sc;
    shf[tid] = be[tid] - mean * sc;
  }
  __syncthreads();
  int i = blockIdx.x * 256 + tid;   // NN*8 exactly
  int n = i >> 3, c0 = (i & 7) * 8;
  union { bf16x8 b; unsigned short u[8]; } raw;
  raw.b = *(const bf16x8*)(A + (size_t)n * 64 + c0);
  float v[8];
#pragma unroll
  for (int j = 0; j < 8; ++j) v[j] = fmaf(bf2f(raw.u[j]), scl[c0 + j], shf[c0 + j]);
  float* p = hf + (size_t)n * 64 + c0;
  *(float4*)(p)     = make_float4(v[0], v[1], v[2], v[3]);
  *(float4*)(p + 4) = make_float4(v[4], v[5], v[6], v[7]);
}

// ---------------- pool: xpool[batch[n]] += h[n]  (batch sorted) ----------------
__global__ __launch_bounds__(256) void pool_k(const float* __restrict__ h,
                                              const int* __restrict__ batch,
                                              float* __restrict__ xpool) {
  int n0 = blockIdx.x * 16;
  int tid = threadIdx.x;
  int r = tid >> 4, c4 = tid & 15;
  int n = n0 + r;
  float4 v = *(const float4*)(h + (size_t)n * 64 + c4 * 4);
  __shared__ int gfirst, gsame;
  __shared__ float red[16][64];
  if (tid == 0) {
    gfirst = batch[n0];
    gsame = (batch[n0] == batch[n0 + 15]) ? 1 : 0;
  }
  *(float4*)&red[r][c4 * 4] = v;
  __syncthreads();
  if (gsame) {
#pragma unroll
    for (int off = 8; off >= 1; off >>= 1) {
      if (r < off) {
        float4 a = *(float4*)&red[r][c4 * 4];
        float4 b = *(float4*)&red[r + off][c4 * 4];
        *(float4*)&red[r][c4 * 4] = make_float4(a.x + b.x, a.y + b.y, a.z + b.z, a.w + b.w);
      }
      __syncthreads();
    }
    if (r == 0) {
      float* p = xpool + (size_t)gfirst * 64 + c4 * 4;
      float4 a = *(float4*)&red[0][c4 * 4];
      atomicAdd(p + 0, a.x); atomicAdd(p + 1, a.y);
      atomicAdd(p + 2, a.z); atomicAdd(p + 3, a.w);
    }
  } else {
    int g = batch[n];
    float* p = xpool + (size_t)g * 64 + c4 * 4;
    atomicAdd(p + 0, v.x); atomicAdd(p + 1, v.y);
    atomicAdd(p + 2, v.z); atomicAdd(p + 3, v.w);
  }
}

extern "C" void kernel_launch(void* const* d_in, const int* in_sizes, int n_in,
                              void* d_out, int out_size, void* d_ws, size_t ws_size,
                              hipStream_t stream) {
  const int* batch = (const int*)d_in[0];
  const int* x = (const int*)d_in[1];
  const int* ei = (const int*)d_in[2];
  const int* eattr = (const int*)d_in[3];
  const float* atom_emb = (const float*)d_in[4];
  const float* bond_emb = (const float*)d_in[5];
  const float* W1 = (const float*)d_in[6];
  const float* b1 = (const float*)d_in[7];
  const float* g1 = (const float*)d_in[8];
  const float* be1 = (const float*)d_in[9];
  const float* W2 = (const float*)d_in[10];
  const float* b2 = (const float*)d_in[11];
  const float* gbn = (const float*)d_in[12];
  const float* bbn = (const float*)d_in[13];

  float* out = (float*)d_out;
  float* xpool = out;               // 256*64
  float* hf = out + NG * 64;        // final f32 h lives directly in output

  char* ws = (char*)d_ws;
  unsigned short* A   = (unsigned short*)(ws);                      // NP*64 bf16 (h / z2)
  unsigned short* z1b = (unsigned short*)(ws + 12804096);           // NP*128 bf16 = 25.6 MB
  float* statf        = (float*)(ws + 38412288);                    // 5*3072 f32 = 61440 B
  unsigned short* Wt1 = (unsigned short*)(ws + 38473728);           // 5*128*64 bf16
  unsigned short* Wt2 = (unsigned short*)(ws + 38555648);           // 5*64*128 bf16
  int* rowstart       = (int*)(ws + 38637568);                      // NP+1 ints
  int* epack          = (int*)(ws + 39038080);                      // NE ints -> ends ~42.2MB
  // CSR build temporaries alias z1b region (dead until first aggr_gemm1)
  int* cnt    = (int*)(ws + 12804096);
  int* cursor = (int*)(ws + 12804096 + 1048576);
  int* bsum   = (int*)(ws + 12804096 + 2097152);
  int* bofs   = bsum + 128;

  init_h_k<<<NN * 8 / 256, 256, 0, stream>>>(x, atom_emb, A);
  wconv_k<<<(2 * NL * 128 * 64 + 255) / 256, 256, 0, stream>>>(W1, W2, Wt1, Wt2);

  // ---- CSR build (edge structure shared by all layers) ----
  hipMemsetAsync(cnt, 0, (size_t)NN * 4, stream);
  hist_k<<<(NE + 255) / 256, 256, 0, stream>>>(ei, cnt);
  scan1_k<<<98, 256, 0, stream>>>(cnt, rowstart, bsum);
  scan2_k<<<1, 64, 0, stream>>>(bsum, bofs, 98);
  scan3_k<<<(NP + 256) / 256, 256, 0, stream>>>(rowstart, bofs, cursor);
  scatter_k<<<8 * ((NE + 255) / 256), 256, 0, stream>>>(ei, eattr, cursor, epack);

  hipMemsetAsync(statf, 0, 61440, stream);
  for (int l = 0; l < NL; ++l) {
    float* stat1 = statf + (size_t)l * 3072;
    float* stat2 = statf + (size_t)l * 3072 + 2048;
    float* stat2p = statf + (size_t)(l - 1) * 3072 + 2048;
    if (l == 0)
      aggr_gemm1_k<0><<<(NP / 64), 256, 0, stream>>>(rowstart, epack, bond_emb, A,
                                                     statf, gbn, bbn,
                                                     Wt1, b1, z1b, stat1);
    else
      aggr_gemm1_k<1><<<(NP / 64), 256, 0, stream>>>(rowstart, epack, bond_emb, A,
                                                     stat2p, gbn + (size_t)(l - 1) * 64,
                                                     bbn + (size_t)(l - 1) * 64,
                                                     Wt1 + (size_t)l * 128 * 64,
                                                     b1 + (size_t)l * 128, z1b, stat1);
    gemm2_k<<<(NP / 64), 256, 0, stream>>>(z1b, Wt2 + (size_t)l * 64 * 128,
                                           b2 + (size_t)l * 64,
                                           g1 + (size_t)l * 128, be1 + (size_t)l * 128,
                                           stat1, A, stat2);
  }

  bn_final_k<<<NN * 8 / 256, 256, 0, stream>>>(A, statf + (size_t)(NL - 1) * 3072 + 2048,
                                               gbn + (size_t)(NL - 1) * 64,
                                               bbn + (size_t)(NL - 1) * 64, hf);

  hipMemsetAsync(xpool, 0, (size_t)NG * 64 * 4, stream);
  pool_k<<<NN / 16, 256, 0, stream>>>(hf, batch, xpool);
}